// Round 11
// baseline (595.759 us; speedup 1.0000x reference)
//
#include <hip/hip_runtime.h>

#define HID 64
#define N_GRAPHS_C 512
#define BSHIFT 8          // 256 nodes per coarse bucket
#define NBUCK_MAX 512
#define CAP 3264          // bucket capacity (mean 2560 + ~14 sigma)
#define EPB 4096          // edges per block in bin pass

typedef unsigned short u16;
typedef unsigned int u32;
typedef unsigned long long u64;

__device__ __forceinline__ float bf2f(u16 u) {
    union { u32 i; float f; } v; v.i = ((u32)u) << 16; return v.f;
}
__device__ __forceinline__ u16 f2bf(float f) {
    union { float f; u32 i; } v; v.f = f;
    u32 x = v.i;
    return (u16)((x + 0x7fffu + ((x >> 16) & 1u)) >> 16);  // RNE
}

// ---------------- binning: packed u32 pairs, bucket-grouped -----------------
// pack = (local_dst << 17) | src   (local_dst < 256, src < 131072)

__global__ void bin_pairs(const int* __restrict__ src, const int* __restrict__ dst,
                          int* __restrict__ gcursor, u32* __restrict__ pairs,
                          int nE, int nbuck) {
    __shared__ int lh[NBUCK_MAX];
    __shared__ int lbase[NBUCK_MAX];
    int t = threadIdx.x;
    lh[t] = 0; lh[t + 256] = 0;
    __syncthreads();
    int base = blockIdx.x * EPB;
    u32 pk[16]; int rj[16], bj[16];
    #pragma unroll
    for (int j = 0; j < 16; ++j) {
        int e = base + j * 256 + t;
        if (e < nE) {
            int s = src[e], d = dst[e];
            bj[j] = d >> BSHIFT;
            pk[j] = ((u32)(d & 255) << 17) | (u32)s;
            rj[j] = atomicAdd(&lh[bj[j]], 1);
        } else {
            bj[j] = -1;
        }
    }
    __syncthreads();
    for (int b = t; b < nbuck; b += 256)
        lbase[b] = (lh[b] > 0) ? atomicAdd(&gcursor[b], lh[b]) : 0;
    __syncthreads();
    #pragma unroll
    for (int j = 0; j < 16; ++j) {
        if (bj[j] >= 0) {
            int pos = bj[j] * CAP + lbase[bj[j]] + rj[j];
            pairs[pos] = pk[j];
        }
    }
}

// ---------------- node_prep: degree hist -> dinv + pre-scaled x -------------

__global__ void node_prep(const u32* __restrict__ pairs, const int* __restrict__ gcursor,
                          const float* __restrict__ x, float* __restrict__ dinv,
                          float4* __restrict__ xs, int n) {
    __shared__ int hist[256];
    int t = threadIdx.x;
    int b = blockIdx.x;
    hist[t] = 0;
    __syncthreads();
    int pbeg = b * CAP, cnt = gcursor[b];
    for (int i = t; i < cnt; i += 256)
        atomicAdd(&hist[pairs[pbeg + i] >> 17], 1);
    __syncthreads();
    int node = (b << BSHIFT) + t;
    if (node < n) {
        float dv = rsqrtf((float)(hist[t] + 1));   // +1 self-loop
        dinv[node] = dv;
        xs[node] = make_float4(x[3*node]*dv, x[3*node+1]*dv, x[3*node+2]*dv, dv);
    }
}

// ---------------- layer 1: edge-parallel 3-dim aggregation ------------------
// One block per bucket; thread per edge; 3-plane fp32 LDS accumulators.

__global__ void agg_l1(const u32* __restrict__ pairs, const int* __restrict__ gcursor,
                       const float4* __restrict__ xs, float4* __restrict__ agg4, int n) {
    __shared__ float a0[256], a1[256], a2[256];
    int t = threadIdx.x;
    int b = blockIdx.x;
    a0[t] = 0.0f; a1[t] = 0.0f; a2[t] = 0.0f;
    __syncthreads();
    int pbeg = b * CAP, cnt = gcursor[b];
    int k = t;
    for (; k + 768 < cnt; k += 1024) {      // volley of 4 for MLP
        u32 p0 = pairs[pbeg + k];
        u32 p1 = pairs[pbeg + k + 256];
        u32 p2 = pairs[pbeg + k + 512];
        u32 p3 = pairs[pbeg + k + 768];
        float4 v0 = xs[p0 & 0x1FFFFu];
        float4 v1 = xs[p1 & 0x1FFFFu];
        float4 v2 = xs[p2 & 0x1FFFFu];
        float4 v3 = xs[p3 & 0x1FFFFu];
        int d0 = p0 >> 17, d1 = p1 >> 17, d2 = p2 >> 17, d3 = p3 >> 17;
        atomicAdd(&a0[d0], v0.x); atomicAdd(&a1[d0], v0.y); atomicAdd(&a2[d0], v0.z);
        atomicAdd(&a0[d1], v1.x); atomicAdd(&a1[d1], v1.y); atomicAdd(&a2[d1], v1.z);
        atomicAdd(&a0[d2], v2.x); atomicAdd(&a1[d2], v2.y); atomicAdd(&a2[d2], v2.z);
        atomicAdd(&a0[d3], v3.x); atomicAdd(&a1[d3], v3.y); atomicAdd(&a2[d3], v3.z);
    }
    for (; k < cnt; k += 256) {
        u32 p = pairs[pbeg + k];
        float4 v = xs[p & 0x1FFFFu];
        int d = p >> 17;
        atomicAdd(&a0[d], v.x); atomicAdd(&a1[d], v.y); atomicAdd(&a2[d], v.z);
    }
    __syncthreads();
    int node = (b << BSHIFT) + t;
    if (node < n) {
        float4 self = xs[node];
        agg4[node] = make_float4(a0[t] + self.x, a1[t] + self.y, a2[t] + self.z, self.w);
    }
}

// ---------------- fused expand + layer-2 matmul (32 nodes/block) ------------

#define MM2_NODES 32
__global__ void mm2f(const float4* __restrict__ agg4, const float* __restrict__ W1,
                     const float* __restrict__ b1, const float* __restrict__ W2,
                     u16* __restrict__ A16, int n) {
    __shared__ float w[HID * HID];         // 16 KB
    __shared__ float h[MM2_NODES * HID];   // 8 KB
    __shared__ float dd[MM2_NODES];
    int t = threadIdx.x;
    for (int i = t; i < HID * HID; i += 256) w[i] = W2[i];
    int base = blockIdx.x * MM2_NODES;
    for (int i = t; i < MM2_NODES * HID; i += 256) {
        int node = base + (i >> 6);
        int f = i & 63;
        float hv = 0.0f;
        if (node < n) {
            float4 a = agg4[node];
            float v = (a.x * W1[f] + a.y * W1[HID + f] + a.z * W1[2 * HID + f]) * a.w + b1[f];
            hv = v > 0.0f ? v : 0.0f;
            if (f == 0) dd[i >> 6] = a.w;
        }
        h[i] = hv;
    }
    __syncthreads();
    int f = t & 63, g = t >> 6;   // wave g handles nodes base + g*8 .. +7
    float acc[8];
    #pragma unroll
    for (int j = 0; j < 8; ++j) acc[j] = 0.0f;
    #pragma unroll 4
    for (int k = 0; k < HID; ++k) {
        float wk = w[k * HID + f];
        #pragma unroll
        for (int j = 0; j < 8; ++j) acc[j] += h[(g * 8 + j) * HID + k] * wk;
    }
    #pragma unroll
    for (int j = 0; j < 8; ++j) {
        int node = base + g * 8 + j;
        if (node < n) A16[(size_t)node * HID + f] = f2bf(acc[j] * dd[g * 8 + j]);
    }
}

// ---------------- layer 2: edge-parallel aggregation, 64KB LDS tile ---------
// One block per bucket (512 thr = 8 waves). Wave handles one edge per volley
// slot: lane = feature, coalesced 128B row load, fp32 LDS atomic accumulate.

#define L2BT 512
__global__ void agg_l2(const u32* __restrict__ pairs, const int* __restrict__ gcursor,
                       const u16* __restrict__ A16, const float* __restrict__ dinv,
                       const float* __restrict__ bias, u16* __restrict__ H2, int n) {
    __shared__ float acc[256 * HID];   // exactly 64 KB
    int t = threadIdx.x;
    int b = blockIdx.x;
    for (int i = t; i < 256 * HID; i += L2BT) acc[i] = 0.0f;
    __syncthreads();
    int pbeg = b * CAP, cnt = gcursor[b];
    int w = t >> 6;                    // wave 0..7
    int f = t & 63;
    const int NW = L2BT / 64;          // 8
    int k = w;
    for (; k + 3 * NW < cnt; k += 4 * NW) {   // volley of 4 edges per wave
        u32 p0 = pairs[pbeg + k];
        u32 p1 = pairs[pbeg + k + NW];
        u32 p2 = pairs[pbeg + k + 2 * NW];
        u32 p3 = pairs[pbeg + k + 3 * NW];
        u16 r0 = A16[((size_t)(p0 & 0x1FFFFu) << 6) + f];
        u16 r1 = A16[((size_t)(p1 & 0x1FFFFu) << 6) + f];
        u16 r2 = A16[((size_t)(p2 & 0x1FFFFu) << 6) + f];
        u16 r3 = A16[((size_t)(p3 & 0x1FFFFu) << 6) + f];
        atomicAdd(&acc[((p0 >> 17) << 6) + f], bf2f(r0));
        atomicAdd(&acc[((p1 >> 17) << 6) + f], bf2f(r1));
        atomicAdd(&acc[((p2 >> 17) << 6) + f], bf2f(r2));
        atomicAdd(&acc[((p3 >> 17) << 6) + f], bf2f(r3));
    }
    for (; k < cnt; k += NW) {
        u32 p = pairs[pbeg + k];
        u16 r = A16[((size_t)(p & 0x1FFFFu) << 6) + f];
        atomicAdd(&acc[((p >> 17) << 6) + f], bf2f(r));
    }
    __syncthreads();
    int nbeg = b << BSHIFT;
    for (int i = t; i < 256 * HID; i += L2BT) {
        int node = nbeg + (i >> 6);
        if (node < n) {
            int ff = i & 63;
            float self = bf2f(A16[((size_t)node << 6) + ff]);
            float v = (acc[i] + self) * dinv[node] + bias[ff];
            H2[((size_t)node << 6) + ff] = f2bf(fmaxf(v, 0.0f));
        }
    }
}

// ---------------- global mean pool: one block per graph, no atomics ---------

__device__ __forceinline__ int lower_bound(const int* __restrict__ a, int n, int key) {
    int lo = 0, hi = n;
    while (lo < hi) {
        int mid = (lo + hi) >> 1;
        if (a[mid] < key) lo = mid + 1; else hi = mid;
    }
    return lo;
}

__global__ void pool_graph(const u16* __restrict__ H16, const int* __restrict__ batch,
                           float* __restrict__ out, int n) {
    int g = blockIdx.x;
    int t = threadIdx.x;
    int lo = lower_bound(batch, n, g);
    int hi = lower_bound(batch, n, g + 1);
    int cntN = hi - lo;
    int sid = t >> 4;                  // stream 0..15
    int m = t & 15;                    // feature quad
    float a0 = 0.f, a1 = 0.f, a2 = 0.f, a3 = 0.f;
    int i = lo + sid;
    for (; i + 16 < hi; i += 32) {
        u64 r0 = *(const u64*)(H16 + ((size_t)i << 6) + (m << 2));
        u64 r1 = *(const u64*)(H16 + ((size_t)(i + 16) << 6) + (m << 2));
        u32 l0 = (u32)r0, h0 = (u32)(r0 >> 32);
        u32 l1 = (u32)r1, h1 = (u32)(r1 >> 32);
        a0 += bf2f((u16)(l0 & 0xffffu)) + bf2f((u16)(l1 & 0xffffu));
        a1 += bf2f((u16)(l0 >> 16))     + bf2f((u16)(l1 >> 16));
        a2 += bf2f((u16)(h0 & 0xffffu)) + bf2f((u16)(h1 & 0xffffu));
        a3 += bf2f((u16)(h0 >> 16))     + bf2f((u16)(h1 >> 16));
    }
    if (i < hi) {
        u64 r0 = *(const u64*)(H16 + ((size_t)i << 6) + (m << 2));
        u32 l0 = (u32)r0, h0 = (u32)(r0 >> 32);
        a0 += bf2f((u16)(l0 & 0xffffu));
        a1 += bf2f((u16)(l0 >> 16));
        a2 += bf2f((u16)(h0 & 0xffffu));
        a3 += bf2f((u16)(h0 >> 16));
    }
    a0 += __shfl_xor(a0, 16, 64); a0 += __shfl_xor(a0, 32, 64);
    a1 += __shfl_xor(a1, 16, 64); a1 += __shfl_xor(a1, 32, 64);
    a2 += __shfl_xor(a2, 16, 64); a2 += __shfl_xor(a2, 32, 64);
    a3 += __shfl_xor(a3, 16, 64); a3 += __shfl_xor(a3, 32, 64);
    __shared__ float smf[4 * HID];
    int wave = t >> 6, lane = t & 63;
    if (lane < 16) {
        smf[wave * HID + 4 * lane + 0] = a0;
        smf[wave * HID + 4 * lane + 1] = a1;
        smf[wave * HID + 4 * lane + 2] = a2;
        smf[wave * HID + 4 * lane + 3] = a3;
    }
    __syncthreads();
    if (t < HID) {
        float s = smf[t] + smf[HID + t] + smf[2 * HID + t] + smf[3 * HID + t];
        out[(size_t)g * HID + t] = s / fmaxf((float)cntN, 1.0f);
    }
}

// ---------------- launcher ----------------

extern "C" void kernel_launch(void* const* d_in, const int* in_sizes, int n_in,
                              void* d_out, int out_size, void* d_ws, size_t ws_size,
                              hipStream_t stream) {
    const float* x  = (const float*)d_in[0];
    const float* W1 = (const float*)d_in[1];
    const float* b1 = (const float*)d_in[2];
    const float* W2 = (const float*)d_in[3];
    const float* b2 = (const float*)d_in[4];
    const int*   ei = (const int*)d_in[5];
    const int*   batch = (const int*)d_in[6];

    const int n  = in_sizes[0] / 3;   // 100000
    const int nE = in_sizes[5] / 2;   // 1000000
    const int* src = ei;
    const int* dst = ei + nE;
    const int nbuck = (n + ((1 << BSHIFT) - 1)) >> BSHIFT;   // 391
    const int nGraphs = out_size / HID;                      // 512

    // workspace layout (no aliasing; pairs persists through agg_l2)
    char* p = (char*)d_ws;
    int*    gcursor = (int*)p;                p += 2048;
    u32*    pairs   = (u32*)p;                p += (size_t)nbuck * CAP * 4;  // 5.1 MB
    float*  dinv    = (float*)p;              p += (size_t)n * 4;
    float4* xs      = (float4*)p;             p += (size_t)n * 16;
    float4* agg4    = (float4*)p;             p += (size_t)n * 16;
    u16*    A16     = (u16*)p;                p += (size_t)n * HID * 2;
    u16*    H2      = (u16*)p;                p += (size_t)n * HID * 2;

    const int BT = 256;
    const int gridE2   = (nE + EPB - 1) / EPB;              // 245
    const int gridMM2  = (n + MM2_NODES - 1) / MM2_NODES;   // 3125

    hipMemsetAsync(gcursor, 0, 2048, stream);
    bin_pairs<<<gridE2, BT, 0, stream>>>(src, dst, gcursor, pairs, nE, nbuck);
    node_prep<<<nbuck, BT, 0, stream>>>(pairs, gcursor, x, dinv, xs, n);

    // layer 1 (edge-parallel 3-dim aggregate), fused expand + layer-2 matmul
    agg_l1<<<nbuck, BT, 0, stream>>>(pairs, gcursor, xs, agg4, n);
    mm2f<<<gridMM2, BT, 0, stream>>>(agg4, W1, b1, W2, A16, n);

    // layer 2 aggregation (edge-parallel, 64KB LDS tile) + epilogue
    agg_l2<<<nbuck, L2BT, 0, stream>>>(pairs, gcursor, A16, dinv, b2, H2, n);

    // pool
    pool_graph<<<nGraphs, BT, 0, stream>>>(H2, batch, (float*)d_out, n);
}

// Round 12
// 171.989 us; speedup vs baseline: 3.4639x; 3.4639x over previous
//
#include <hip/hip_runtime.h>

#define HID 64
#define N_GRAPHS_C 512
#define BSHIFT 8          // 256 nodes per coarse bucket
#define NBUCK_MAX 512
#define CAP 3264          // bucket capacity (mean 2560 + ~12 sigma)
#define EPB 4096          // edges per block in bin pass

typedef unsigned short u16;
typedef unsigned int u32;
typedef unsigned long long u64;

__device__ __forceinline__ float bf2f(u16 u) {
    union { u32 i; float f; } v; v.i = ((u32)u) << 16; return v.f;
}
__device__ __forceinline__ u16 f2bf(float f) {
    union { float f; u32 i; } v; v.f = f;
    u32 x = v.i;
    return (u16)((x + 0x7fffu + ((x >> 16) & 1u)) >> 16);  // RNE
}

// ---------------- CSR build: single-pass binning, packed u32 pairs ----------
// pack = (local_dst << 17) | src   (local_dst < 256 -> 8 bits, src < 131072)

__global__ void bin_pairs(const int* __restrict__ src, const int* __restrict__ dst,
                          int* __restrict__ gcursor, u32* __restrict__ pairs,
                          int nE, int nbuck) {
    __shared__ int lh[NBUCK_MAX];
    __shared__ int lbase[NBUCK_MAX];
    int t = threadIdx.x;
    lh[t] = 0; lh[t + 256] = 0;
    __syncthreads();
    int base = blockIdx.x * EPB;
    u32 pk[16]; int rj[16], bj[16];
    #pragma unroll
    for (int j = 0; j < 16; ++j) {
        int e = base + j * 256 + t;
        if (e < nE) {
            int s = src[e], d = dst[e];
            bj[j] = d >> BSHIFT;
            pk[j] = ((u32)(d & 255) << 17) | (u32)s;
            rj[j] = atomicAdd(&lh[bj[j]], 1);
        } else {
            bj[j] = -1;
        }
    }
    __syncthreads();
    for (int b = t; b < nbuck; b += 256)
        lbase[b] = (lh[b] > 0) ? atomicAdd(&gcursor[b], lh[b]) : 0;
    __syncthreads();
    #pragma unroll
    for (int j = 0; j < 16; ++j) {
        if (bj[j] >= 0) {
            int pos = bj[j] * CAP + lbase[bj[j]] + rj[j];
            pairs[pos] = pk[j];
        }
    }
}

// One block per bucket (256 nodes, 1 node/thread): LDS histogram, LDS scan ->
// (beg,end) + dinv + xs, then LDS-cursor csr fill. Block 0 zeroes pad row n.
__global__ void build_csr(const u32* __restrict__ pairs, const int* __restrict__ gcursor,
                          int* __restrict__ csr_src, int2* __restrict__ off2,
                          float* __restrict__ dinv, const float* __restrict__ x,
                          float4* __restrict__ xs, u16* __restrict__ A16, int n) {
    __shared__ int hist[256];
    __shared__ int tmp[256];
    int t = threadIdx.x;
    int b = blockIdx.x;
    int pbeg = b * CAP;
    int pend = pbeg + gcursor[b];
    hist[t] = 0;
    if (b == 0 && t < 32) ((u32*)(A16 + (size_t)n * HID))[t] = 0;  // zero pad row
    __syncthreads();
    for (int i = pbeg + t; i < pend; i += 256)
        atomicAdd(&hist[pairs[i] >> 17], 1);
    __syncthreads();
    int v = hist[t];
    tmp[t] = v;
    __syncthreads();
    for (int d = 1; d < 256; d <<= 1) {
        int add = (t >= d) ? tmp[t - d] : 0;
        __syncthreads();
        tmp[t] += add;
        __syncthreads();
    }
    int e = pbeg + tmp[t] - v;   // exclusive
    int node = (b << BSHIFT) + t;
    if (node < n) {
        float dv = rsqrtf((float)(v + 1));
        off2[node] = make_int2(e, e + v);
        dinv[node] = dv;
        xs[node] = make_float4(x[3*node]*dv, x[3*node+1]*dv, x[3*node+2]*dv, dv);
    }
    hist[t] = e;                 // repurpose as fill cursor
    __syncthreads();
    for (int i = pbeg + t; i < pend; i += 256) {
        u32 p = pairs[i];
        int pos = atomicAdd(&hist[p >> 17], 1);
        csr_src[pos] = (int)(p & 0x1FFFFu);
    }
}

// ---------------- layer 1: 3-dim aggregation (thread per node) --------------

__global__ void agg3(const float4* __restrict__ xs, const int* __restrict__ csr_src,
                     const int2* __restrict__ off2, float4* __restrict__ agg4, int n) {
    int node = blockIdx.x * blockDim.x + threadIdx.x;
    if (node >= n) return;
    int2 be = off2[node];
    int beg = be.x, end = be.y;
    float4 self = xs[node];
    float a0 = 0.f, a1 = 0.f, a2 = 0.f;
    for (int k = beg; k < end; k += 8) {
        int e1 = end - 1;
        int idx[8];
        float4 v[8];
        #pragma unroll
        for (int j = 0; j < 8; ++j) idx[j] = csr_src[min(k + j, e1)];
        #pragma unroll
        for (int j = 0; j < 8; ++j) v[j] = xs[idx[j]];
        #pragma unroll
        for (int j = 0; j < 8; ++j) {
            if (k + j < end) { a0 += v[j].x; a1 += v[j].y; a2 += v[j].z; }
        }
    }
    agg4[node] = make_float4(a0 + self.x, a1 + self.y, a2 + self.z, self.w);
}

// ---------------- fused expand + layer-2 matmul (32 nodes/block) ------------

#define MM2_NODES 32
__global__ void mm2f(const float4* __restrict__ agg4, const float* __restrict__ W1,
                     const float* __restrict__ b1, const float* __restrict__ W2,
                     u16* __restrict__ A16, int n) {
    __shared__ float w[HID * HID];         // 16 KB
    __shared__ float h[MM2_NODES * HID];   // 8 KB
    __shared__ float dd[MM2_NODES];
    int t = threadIdx.x;
    for (int i = t; i < HID * HID; i += 256) w[i] = W2[i];
    int base = blockIdx.x * MM2_NODES;
    for (int i = t; i < MM2_NODES * HID; i += 256) {
        int node = base + (i >> 6);
        int f = i & 63;
        float hv = 0.0f;
        if (node < n) {
            float4 a = agg4[node];
            float v = (a.x * W1[f] + a.y * W1[HID + f] + a.z * W1[2 * HID + f]) * a.w + b1[f];
            hv = v > 0.0f ? v : 0.0f;
            if (f == 0) dd[i >> 6] = a.w;
        }
        h[i] = hv;
    }
    __syncthreads();
    int f = t & 63, g = t >> 6;   // wave g handles nodes base + g*8 .. +7
    float acc[8];
    #pragma unroll
    for (int j = 0; j < 8; ++j) acc[j] = 0.0f;
    #pragma unroll 4
    for (int k = 0; k < HID; ++k) {
        float wk = w[k * HID + f];
        #pragma unroll
        for (int j = 0; j < 8; ++j) acc[j] += h[(g * 8 + j) * HID + k] * wk;
    }
    #pragma unroll
    for (int j = 0; j < 8; ++j) {
        int node = base + g * 8 + j;
        if (node < n) A16[(size_t)node * HID + f] = f2bf(acc[j] * dd[g * 8 + j]);
    }
}

// ---------------- layer-2 gather: 4 nodes/wave, u64 lanes, zero-row pad -----

__global__ void gather_nodes(const u16* __restrict__ A16, const float* __restrict__ dinv,
                             const int* __restrict__ csr_src, const int2* __restrict__ off2,
                             const float* __restrict__ bias,
                             u16* __restrict__ H16, int n) {
    int t = threadIdx.x;
    int waveq = t >> 4;                // 0..15: quarter index within block
    int m = t & 15;                    // feature quad: features 4m..4m+3
    int qbase = t & 48;                // base lane of my quarter within the wave
    int node = blockIdx.x * 16 + waveq;
    if (node >= n) return;             // quarter-uniform exit, no barriers below
    int2 be = off2[node];
    int beg = be.x, end = be.y;
    u64 selfrow = *(const u64*)(A16 + ((size_t)node << 6) + (m << 2));
    u32 slo = (u32)selfrow, shi = (u32)(selfrow >> 32);
    float acc0 = bf2f((u16)(slo & 0xffffu));
    float acc1 = bf2f((u16)(slo >> 16));
    float acc2 = bf2f((u16)(shi & 0xffffu));
    float acc3 = bf2f((u16)(shi >> 16));
    const char* Ab = (const char*)A16;
    u32 laneoff = (u32)(m << 3);       // byte offset of my quad within a row
    for (int k = beg; k < end; k += 16) {
        int nIdx = end - k;            // >=16 means full chunk
        int myIdx = (m < nIdx) ? csr_src[k + m] : n;   // pad -> zero row
        #pragma unroll
        for (int j0 = 0; j0 < 16; j0 += 8) {
            int ss[8]; u64 rows[8];
            #pragma unroll
            for (int j = 0; j < 8; ++j)
                ss[j] = __shfl(myIdx, qbase + j0 + j, 64);
            #pragma unroll
            for (int j = 0; j < 8; ++j)
                rows[j] = *(const u64*)(Ab + (((u32)ss[j] << 7) | laneoff));
            #pragma unroll
            for (int j = 0; j < 8; ++j) {
                u32 lo = (u32)rows[j], hi = (u32)(rows[j] >> 32);
                acc0 += bf2f((u16)(lo & 0xffffu));
                acc1 += bf2f((u16)(lo >> 16));
                acc2 += bf2f((u16)(hi & 0xffffu));
                acc3 += bf2f((u16)(hi >> 16));
            }
        }
    }
    float ddv = dinv[node];
    float4 bb = *(const float4*)(bias + (m << 2));
    float v0 = fmaxf(acc0 * ddv + bb.x, 0.0f);
    float v1 = fmaxf(acc1 * ddv + bb.y, 0.0f);
    float v2 = fmaxf(acc2 * ddv + bb.z, 0.0f);
    float v3 = fmaxf(acc3 * ddv + bb.w, 0.0f);
    u64 outp = (u64)f2bf(v0) | ((u64)f2bf(v1) << 16)
             | ((u64)f2bf(v2) << 32) | ((u64)f2bf(v3) << 48);
    *(u64*)(H16 + ((size_t)node << 6) + (m << 2)) = outp;
}

// ---------------- graph ranges: one parallel lower_bound per thread ---------

__device__ __forceinline__ int lower_bound(const int* __restrict__ a, int n, int key) {
    int lo = 0, hi = n;
    while (lo < hi) {
        int mid = (lo + hi) >> 1;
        if (a[mid] < key) lo = mid + 1; else hi = mid;
    }
    return lo;
}

__global__ void graph_ranges(const int* __restrict__ batch, int* __restrict__ gstart,
                             int n, int nGraphs) {
    for (int g = threadIdx.x; g <= nGraphs; g += blockDim.x)
        gstart[g] = lower_bound(batch, n, g);
}

// ---------------- global mean pool: one block per graph, no atomics ---------

__global__ void pool_graph(const u16* __restrict__ H16, const int* __restrict__ gstart,
                           float* __restrict__ out, int n) {
    int g = blockIdx.x;
    int t = threadIdx.x;
    int lo = gstart[g];
    int hi = gstart[g + 1];
    int cntN = hi - lo;
    int sid = t >> 4;                  // stream 0..15
    int m = t & 15;                    // feature quad
    float a0 = 0.f, a1 = 0.f, a2 = 0.f, a3 = 0.f;
    int i = lo + sid;
    for (; i + 16 < hi; i += 32) {     // unroll x2 for MLP
        u64 r0 = *(const u64*)(H16 + ((size_t)i << 6) + (m << 2));
        u64 r1 = *(const u64*)(H16 + ((size_t)(i + 16) << 6) + (m << 2));
        u32 l0 = (u32)r0, h0 = (u32)(r0 >> 32);
        u32 l1 = (u32)r1, h1 = (u32)(r1 >> 32);
        a0 += bf2f((u16)(l0 & 0xffffu)) + bf2f((u16)(l1 & 0xffffu));
        a1 += bf2f((u16)(l0 >> 16))     + bf2f((u16)(l1 >> 16));
        a2 += bf2f((u16)(h0 & 0xffffu)) + bf2f((u16)(h1 & 0xffffu));
        a3 += bf2f((u16)(h0 >> 16))     + bf2f((u16)(h1 >> 16));
    }
    if (i < hi) {
        u64 r0 = *(const u64*)(H16 + ((size_t)i << 6) + (m << 2));
        u32 l0 = (u32)r0, h0 = (u32)(r0 >> 32);
        a0 += bf2f((u16)(l0 & 0xffffu));
        a1 += bf2f((u16)(l0 >> 16));
        a2 += bf2f((u16)(h0 & 0xffffu));
        a3 += bf2f((u16)(h0 >> 16));
    }
    // reduce the 4 quarters within each wave (lanes differ in bits 4,5)
    a0 += __shfl_xor(a0, 16, 64); a0 += __shfl_xor(a0, 32, 64);
    a1 += __shfl_xor(a1, 16, 64); a1 += __shfl_xor(a1, 32, 64);
    a2 += __shfl_xor(a2, 16, 64); a2 += __shfl_xor(a2, 32, 64);
    a3 += __shfl_xor(a3, 16, 64); a3 += __shfl_xor(a3, 32, 64);
    __shared__ float smf[4 * HID];
    int wave = t >> 6, lane = t & 63;
    if (lane < 16) {
        smf[wave * HID + 4 * lane + 0] = a0;
        smf[wave * HID + 4 * lane + 1] = a1;
        smf[wave * HID + 4 * lane + 2] = a2;
        smf[wave * HID + 4 * lane + 3] = a3;
    }
    __syncthreads();
    if (t < HID) {
        float s = smf[t] + smf[HID + t] + smf[2 * HID + t] + smf[3 * HID + t];
        out[(size_t)g * HID + t] = s / fmaxf((float)cntN, 1.0f);
    }
}

// ---------------- launcher ----------------

extern "C" void kernel_launch(void* const* d_in, const int* in_sizes, int n_in,
                              void* d_out, int out_size, void* d_ws, size_t ws_size,
                              hipStream_t stream) {
    const float* x  = (const float*)d_in[0];
    const float* W1 = (const float*)d_in[1];
    const float* b1 = (const float*)d_in[2];
    const float* W2 = (const float*)d_in[3];
    const float* b2 = (const float*)d_in[4];
    const int*   ei = (const int*)d_in[5];
    const int*   batch = (const int*)d_in[6];

    const int n  = in_sizes[0] / 3;   // 100000
    const int nE = in_sizes[5] / 2;   // 1000000
    const int* src = ei;
    const int* dst = ei + nE;
    const int nbuck = (n + ((1 << BSHIFT) - 1)) >> BSHIFT;   // 391
    const int nGraphs = out_size / HID;                      // 512

    // workspace layout
    char* p = (char*)d_ws;
    int*    gcursor = (int*)p;                p += 2048;
    int*    gstart  = (int*)p;                p += 4096;   // 513 ints (padded)
    int*    csr_src = (int*)p;                p += (size_t)nbuck * CAP * 4;  // 5.1 MB
    int2*   off2    = (int2*)p;               p += (size_t)n * 8;
    float*  dinv    = (float*)p;              p += (size_t)n * 4;
    float4* xs      = (float4*)p;             p += (size_t)n * 16;
    float4* agg4    = (float4*)p;             p += (size_t)n * 16;
    u16*    A16     = (u16*)p;                p += (size_t)(n + 1) * HID * 2; // +pad row
    u16*    H2      = (u16*)p;                p += (size_t)n * HID * 2;
    u32*    pairs   = (u32*)A16;              // 5.1 MB alias; dead before mm2f

    const int BT = 256;
    const int gridNode = (n + BT - 1) / BT;              // 391
    const int gridE2   = (nE + EPB - 1) / EPB;           // 245
    const int gridMM2  = (n + MM2_NODES - 1) / MM2_NODES;// 3125
    const int gridGath = (n + 15) / 16;                  // 6250

    // CSR build (single-pass binning) + dinv + xs + pad-row zero
    hipMemsetAsync(gcursor, 0, 2048, stream);
    bin_pairs<<<gridE2, BT, 0, stream>>>(src, dst, gcursor, pairs, nE, nbuck);
    build_csr<<<nbuck, BT, 0, stream>>>(pairs, gcursor, csr_src, off2, dinv, x, xs, A16, n);

    // graph ranges for pool (independent of the above; cheap single block)
    graph_ranges<<<1, 512, 0, stream>>>(batch, gstart, n, nGraphs);

    // layer 1 aggregate (3-dim), then fused expand + layer-2 matmul
    agg3<<<gridNode, BT, 0, stream>>>(xs, csr_src, off2, agg4, n);
    mm2f<<<gridMM2, BT, 0, stream>>>(agg4, W1, b1, W2, A16, n);

    // layer-2 gather
    gather_nodes<<<gridGath, BT, 0, stream>>>(A16, dinv, csr_src, off2, b2, H2, n);

    // pool: one block per graph, no atomics, no finalize
    pool_graph<<<nGraphs, BT, 0, stream>>>(H2, gstart, (float*)d_out, n);
}

// Round 13
// 168.927 us; speedup vs baseline: 3.5267x; 1.0181x over previous
//
#include <hip/hip_runtime.h>

#define HID 64
#define N_GRAPHS_C 512
#define BSHIFT 8          // 256 nodes per coarse bucket
#define NBUCK_MAX 512
#define CAP 3264          // bucket capacity (mean 2560 + ~12 sigma)
#define EPB 4096          // edges per block in bin pass

typedef unsigned short u16;
typedef unsigned int u32;
typedef unsigned long long u64;

__device__ __forceinline__ float bf2f(u16 u) {
    union { u32 i; float f; } v; v.i = ((u32)u) << 16; return v.f;
}
__device__ __forceinline__ u16 f2bf(float f) {
    union { float f; u32 i; } v; v.f = f;
    u32 x = v.i;
    return (u16)((x + 0x7fffu + ((x >> 16) & 1u)) >> 16);  // RNE
}

// ---------------- prep: zero cursors + graph ranges (one block) -------------

__device__ __forceinline__ int lower_bound(const int* __restrict__ a, int n, int key) {
    int lo = 0, hi = n;
    while (lo < hi) {
        int mid = (lo + hi) >> 1;
        if (a[mid] < key) lo = mid + 1; else hi = mid;
    }
    return lo;
}

__global__ void prep(int* __restrict__ gcursor, const int* __restrict__ batch,
                     int* __restrict__ gstart, int n, int nGraphs) {
    int t = threadIdx.x;                       // 512 threads
    gcursor[t] = 0;
    for (int g = t; g <= nGraphs; g += 512)
        gstart[g] = lower_bound(batch, n, g);
}

// ---------------- binning: packed u32 pairs, 512-thread blocks --------------
// pack = (local_dst << 17) | src   (local_dst < 256 -> 8 bits, src < 131072)

__global__ void bin_pairs(const int* __restrict__ src, const int* __restrict__ dst,
                          int* __restrict__ gcursor, u32* __restrict__ pairs,
                          int nE, int nbuck) {
    __shared__ int lh[NBUCK_MAX];
    __shared__ int lbase[NBUCK_MAX];
    int t = threadIdx.x;                       // 0..511
    lh[t] = 0;
    __syncthreads();
    int base = blockIdx.x * EPB;
    u32 pk[8]; int rj[8], bj[8];
    #pragma unroll
    for (int j = 0; j < 8; ++j) {
        int e = base + j * 512 + t;
        if (e < nE) {
            int s = src[e], d = dst[e];
            bj[j] = d >> BSHIFT;
            pk[j] = ((u32)(d & 255) << 17) | (u32)s;
            rj[j] = atomicAdd(&lh[bj[j]], 1);
        } else {
            bj[j] = -1;
        }
    }
    __syncthreads();
    if (t < nbuck) lbase[t] = (lh[t] > 0) ? atomicAdd(&gcursor[t], lh[t]) : 0;
    __syncthreads();
    #pragma unroll
    for (int j = 0; j < 8; ++j) {
        if (bj[j] >= 0) {
            int pos = bj[j] * CAP + lbase[bj[j]] + rj[j];
            pairs[pos] = pk[j];
        }
    }
}

// One block per bucket (512 thr): LDS histogram, LDS scan (first 256 thr) ->
// (beg,end) + dinv + xs, then LDS-cursor csr fill. Block 0 zeroes pad row n.
__global__ void build_csr(const u32* __restrict__ pairs, const int* __restrict__ gcursor,
                          int* __restrict__ csr_src, int2* __restrict__ off2,
                          float* __restrict__ dinv, const float* __restrict__ x,
                          float4* __restrict__ xs, u16* __restrict__ A16, int n) {
    __shared__ int hist[256];
    __shared__ int tmp[256];
    int t = threadIdx.x;                       // 0..511
    int b = blockIdx.x;
    int pbeg = b * CAP;
    int pend = pbeg + gcursor[b];
    if (t < 256) hist[t] = 0;
    if (b == 0 && t < 32) ((u32*)(A16 + (size_t)n * HID))[t] = 0;  // zero pad row
    __syncthreads();
    for (int i = pbeg + t; i < pend; i += 512)
        atomicAdd(&hist[pairs[i] >> 17], 1);
    __syncthreads();
    int v = 0;
    if (t < 256) { v = hist[t]; tmp[t] = v; }
    __syncthreads();
    for (int d = 1; d < 256; d <<= 1) {
        int add = (t >= d && t < 256) ? tmp[t - d] : 0;
        __syncthreads();
        if (t < 256) tmp[t] += add;
        __syncthreads();
    }
    if (t < 256) {
        int e = pbeg + tmp[t] - v;             // exclusive
        int node = (b << BSHIFT) + t;
        if (node < n) {
            float dv = rsqrtf((float)(v + 1));
            off2[node] = make_int2(e, e + v);
            dinv[node] = dv;
            xs[node] = make_float4(x[3*node]*dv, x[3*node+1]*dv, x[3*node+2]*dv, dv);
        }
        hist[t] = e;                           // repurpose as fill cursor
    }
    __syncthreads();
    for (int i = pbeg + t; i < pend; i += 512) {
        u32 p = pairs[i];
        int pos = atomicAdd(&hist[p >> 17], 1);
        csr_src[pos] = (int)(p & 0x1FFFFu);
    }
}

// ---------------- layer 1: 3-dim aggregation (thread per node) --------------

__global__ void agg3(const float4* __restrict__ xs, const int* __restrict__ csr_src,
                     const int2* __restrict__ off2, float4* __restrict__ agg4, int n) {
    int node = blockIdx.x * blockDim.x + threadIdx.x;
    if (node >= n) return;
    int2 be = off2[node];
    int beg = be.x, end = be.y;
    float4 self = xs[node];
    float a0 = 0.f, a1 = 0.f, a2 = 0.f;
    for (int k = beg; k < end; k += 8) {
        int e1 = end - 1;
        int idx[8];
        float4 v[8];
        #pragma unroll
        for (int j = 0; j < 8; ++j) idx[j] = csr_src[min(k + j, e1)];
        #pragma unroll
        for (int j = 0; j < 8; ++j) v[j] = xs[idx[j]];
        #pragma unroll
        for (int j = 0; j < 8; ++j) {
            if (k + j < end) { a0 += v[j].x; a1 += v[j].y; a2 += v[j].z; }
        }
    }
    agg4[node] = make_float4(a0 + self.x, a1 + self.y, a2 + self.z, self.w);
}

// ---------------- fused expand + layer-2 matmul (32 nodes/block) ------------

#define MM2_NODES 32
__global__ void mm2f(const float4* __restrict__ agg4, const float* __restrict__ W1,
                     const float* __restrict__ b1, const float* __restrict__ W2,
                     u16* __restrict__ A16, int n) {
    __shared__ float w[HID * HID];         // 16 KB
    __shared__ float h[MM2_NODES * HID];   // 8 KB
    __shared__ float dd[MM2_NODES];
    int t = threadIdx.x;
    for (int i = t; i < HID * HID; i += 256) w[i] = W2[i];
    int base = blockIdx.x * MM2_NODES;
    for (int i = t; i < MM2_NODES * HID; i += 256) {
        int node = base + (i >> 6);
        int f = i & 63;
        float hv = 0.0f;
        if (node < n) {
            float4 a = agg4[node];
            float v = (a.x * W1[f] + a.y * W1[HID + f] + a.z * W1[2 * HID + f]) * a.w + b1[f];
            hv = v > 0.0f ? v : 0.0f;
            if (f == 0) dd[i >> 6] = a.w;
        }
        h[i] = hv;
    }
    __syncthreads();
    int f = t & 63, g = t >> 6;   // wave g handles nodes base + g*8 .. +7
    float acc[8];
    #pragma unroll
    for (int j = 0; j < 8; ++j) acc[j] = 0.0f;
    #pragma unroll 4
    for (int k = 0; k < HID; ++k) {
        float wk = w[k * HID + f];
        #pragma unroll
        for (int j = 0; j < 8; ++j) acc[j] += h[(g * 8 + j) * HID + k] * wk;
    }
    #pragma unroll
    for (int j = 0; j < 8; ++j) {
        int node = base + g * 8 + j;
        if (node < n) A16[(size_t)node * HID + f] = f2bf(acc[j] * dd[g * 8 + j]);
    }
}

// ---------------- layer-2 gather: 4 nodes/wave, u64 lanes, volley of 8 ------

__global__ void gather_nodes(const u16* __restrict__ A16, const float* __restrict__ dinv,
                             const int* __restrict__ csr_src, const int2* __restrict__ off2,
                             const float* __restrict__ bias,
                             u16* __restrict__ H16, int n) {
    int t = threadIdx.x;
    int waveq = t >> 4;                // 0..15: quarter index within block
    int m = t & 15;                    // feature quad: features 4m..4m+3
    int qbase = t & 48;                // base lane of my quarter within the wave
    int node = blockIdx.x * 16 + waveq;
    if (node >= n) return;             // quarter-uniform exit, no barriers below
    int2 be = off2[node];
    int beg = be.x, end = be.y;
    u64 selfrow = *(const u64*)(A16 + ((size_t)node << 6) + (m << 2));
    u32 slo = (u32)selfrow, shi = (u32)(selfrow >> 32);
    float acc0 = bf2f((u16)(slo & 0xffffu));
    float acc1 = bf2f((u16)(slo >> 16));
    float acc2 = bf2f((u16)(shi & 0xffffu));
    float acc3 = bf2f((u16)(shi >> 16));
    const char* Ab = (const char*)A16;
    u32 laneoff = (u32)(m << 3);       // byte offset of my quad within a row
    for (int k = beg; k < end; k += 8) {
        int lim = min(end - k, 8);
        int myIdx = (m < lim) ? csr_src[k + m] : n;   // pad -> zero row
        int ss[8]; u64 rows[8];
        #pragma unroll
        for (int j = 0; j < 8; ++j)
            ss[j] = __shfl(myIdx, qbase + j, 64);
        #pragma unroll
        for (int j = 0; j < 8; ++j)
            rows[j] = *(const u64*)(Ab + (((u32)ss[j] << 7) | laneoff));
        #pragma unroll
        for (int j = 0; j < 8; ++j) {
            u32 lo = (u32)rows[j], hi = (u32)(rows[j] >> 32);
            acc0 += bf2f((u16)(lo & 0xffffu));
            acc1 += bf2f((u16)(lo >> 16));
            acc2 += bf2f((u16)(hi & 0xffffu));
            acc3 += bf2f((u16)(hi >> 16));
        }
    }
    float ddv = dinv[node];
    float4 bb = *(const float4*)(bias + (m << 2));
    float v0 = fmaxf(acc0 * ddv + bb.x, 0.0f);
    float v1 = fmaxf(acc1 * ddv + bb.y, 0.0f);
    float v2 = fmaxf(acc2 * ddv + bb.z, 0.0f);
    float v3 = fmaxf(acc3 * ddv + bb.w, 0.0f);
    u64 outp = (u64)f2bf(v0) | ((u64)f2bf(v1) << 16)
             | ((u64)f2bf(v2) << 32) | ((u64)f2bf(v3) << 48);
    *(u64*)(H16 + ((size_t)node << 6) + (m << 2)) = outp;
}

// ---------------- global mean pool: one block per graph, no atomics ---------

__global__ void pool_graph(const u16* __restrict__ H16, const int* __restrict__ gstart,
                           float* __restrict__ out, int n) {
    int g = blockIdx.x;
    int t = threadIdx.x;
    int lo = gstart[g];
    int hi = gstart[g + 1];
    int cntN = hi - lo;
    int sid = t >> 4;                  // stream 0..15
    int m = t & 15;                    // feature quad
    float a0 = 0.f, a1 = 0.f, a2 = 0.f, a3 = 0.f;
    int i = lo + sid;
    for (; i + 16 < hi; i += 32) {     // unroll x2 for MLP
        u64 r0 = *(const u64*)(H16 + ((size_t)i << 6) + (m << 2));
        u64 r1 = *(const u64*)(H16 + ((size_t)(i + 16) << 6) + (m << 2));
        u32 l0 = (u32)r0, h0 = (u32)(r0 >> 32);
        u32 l1 = (u32)r1, h1 = (u32)(r1 >> 32);
        a0 += bf2f((u16)(l0 & 0xffffu)) + bf2f((u16)(l1 & 0xffffu));
        a1 += bf2f((u16)(l0 >> 16))     + bf2f((u16)(l1 >> 16));
        a2 += bf2f((u16)(h0 & 0xffffu)) + bf2f((u16)(h1 & 0xffffu));
        a3 += bf2f((u16)(h0 >> 16))     + bf2f((u16)(h1 >> 16));
    }
    if (i < hi) {
        u64 r0 = *(const u64*)(H16 + ((size_t)i << 6) + (m << 2));
        u32 l0 = (u32)r0, h0 = (u32)(r0 >> 32);
        a0 += bf2f((u16)(l0 & 0xffffu));
        a1 += bf2f((u16)(l0 >> 16));
        a2 += bf2f((u16)(h0 & 0xffffu));
        a3 += bf2f((u16)(h0 >> 16));
    }
    a0 += __shfl_xor(a0, 16, 64); a0 += __shfl_xor(a0, 32, 64);
    a1 += __shfl_xor(a1, 16, 64); a1 += __shfl_xor(a1, 32, 64);
    a2 += __shfl_xor(a2, 16, 64); a2 += __shfl_xor(a2, 32, 64);
    a3 += __shfl_xor(a3, 16, 64); a3 += __shfl_xor(a3, 32, 64);
    __shared__ float smf[4 * HID];
    int wave = t >> 6, lane = t & 63;
    if (lane < 16) {
        smf[wave * HID + 4 * lane + 0] = a0;
        smf[wave * HID + 4 * lane + 1] = a1;
        smf[wave * HID + 4 * lane + 2] = a2;
        smf[wave * HID + 4 * lane + 3] = a3;
    }
    __syncthreads();
    if (t < HID) {
        float s = smf[t] + smf[HID + t] + smf[2 * HID + t] + smf[3 * HID + t];
        out[(size_t)g * HID + t] = s / fmaxf((float)cntN, 1.0f);
    }
}

// ---------------- launcher ----------------

extern "C" void kernel_launch(void* const* d_in, const int* in_sizes, int n_in,
                              void* d_out, int out_size, void* d_ws, size_t ws_size,
                              hipStream_t stream) {
    const float* x  = (const float*)d_in[0];
    const float* W1 = (const float*)d_in[1];
    const float* b1 = (const float*)d_in[2];
    const float* W2 = (const float*)d_in[3];
    const float* b2 = (const float*)d_in[4];
    const int*   ei = (const int*)d_in[5];
    const int*   batch = (const int*)d_in[6];

    const int n  = in_sizes[0] / 3;   // 100000
    const int nE = in_sizes[5] / 2;   // 1000000
    const int* src = ei;
    const int* dst = ei + nE;
    const int nbuck = (n + ((1 << BSHIFT) - 1)) >> BSHIFT;   // 391
    const int nGraphs = out_size / HID;                      // 512

    // workspace layout
    char* p = (char*)d_ws;
    int*    gcursor = (int*)p;                p += 2048;
    int*    gstart  = (int*)p;                p += 4096;   // 513 ints (padded)
    int*    csr_src = (int*)p;                p += (size_t)nbuck * CAP * 4;  // 5.1 MB
    int2*   off2    = (int2*)p;               p += (size_t)n * 8;
    float*  dinv    = (float*)p;              p += (size_t)n * 4;
    float4* xs      = (float4*)p;             p += (size_t)n * 16;
    float4* agg4    = (float4*)p;             p += (size_t)n * 16;
    u16*    A16     = (u16*)p;                p += (size_t)(n + 1) * HID * 2; // +pad row
    u16*    H2      = (u16*)p;                p += (size_t)n * HID * 2;
    u32*    pairs   = (u32*)A16;              // 5.1 MB alias; dead before mm2f

    const int BT = 256;
    const int gridNode = (n + BT - 1) / BT;              // 391
    const int gridE2   = (nE + EPB - 1) / EPB;           // 245
    const int gridMM2  = (n + MM2_NODES - 1) / MM2_NODES;// 3125
    const int gridGath = (n + 15) / 16;                  // 6250

    // prep (cursors + graph ranges), binning, csr build
    prep<<<1, 512, 0, stream>>>(gcursor, batch, gstart, n, nGraphs);
    bin_pairs<<<gridE2, 512, 0, stream>>>(src, dst, gcursor, pairs, nE, nbuck);
    build_csr<<<nbuck, 512, 0, stream>>>(pairs, gcursor, csr_src, off2, dinv, x, xs, A16, n);

    // layer 1 aggregate (3-dim), then fused expand + layer-2 matmul
    agg3<<<gridNode, BT, 0, stream>>>(xs, csr_src, off2, agg4, n);
    mm2f<<<gridMM2, BT, 0, stream>>>(agg4, W1, b1, W2, A16, n);

    // layer-2 gather
    gather_nodes<<<gridGath, BT, 0, stream>>>(A16, dinv, csr_src, off2, b2, H2, n);

    // pool
    pool_graph<<<nGraphs, BT, 0, stream>>>(H2, gstart, (float*)d_out, n);
}